// Round 8
// baseline (216.319 us; speedup 1.0000x reference)
//
#include <hip/hip_runtime.h>

#pragma clang fp contract(off)

#define A_TOTAL 65472
#define NB 16
#define NG 32
#define NLVL 5

// 256-anchor ranges are level-uniform: r<192 -> L0, <240 -> L1, <252 -> L2,
// <255 -> L3, r==255 -> L4 (count 192). All counts are multiples of 64.

// Fused kernel: one wave per (b, range). Lanes = anchors. Computes all IoUs,
// writes per-anchor label+regs (no-force assumption), and atomically reduces
// per-(b,g,level) (max IoU, first argmax anchor) into part[].
__global__ __launch_bounds__(256, 4) void fused_kernel(
    const float* __restrict__ bb,       // [NB][NG][4]
    const int* __restrict__ ids,        // [NB][NG]
    const float* __restrict__ anchors,  // [A_TOTAL][4]
    unsigned long long* __restrict__ part, // [NB][NG][NLVL], pre-zeroed
    float* __restrict__ out)            // labels [NB*A] then regs [NB*A*4]
{
    const int wid = threadIdx.x >> 6;
    const int lane = threadIdx.x & 63;
    const int b = blockIdx.x >> 6;              // 64 blocks per image
    const int r = ((blockIdx.x & 63) << 2) + wid; // range 0..255
    const int start = r << 8;
    const int count = (r == 255) ? 192 : 256;
    const int lvl = (r < 192) ? 0 : (r < 240) ? 1 : (r < 252) ? 2 : (r < 255) ? 3 : 4;

    __shared__ float4 sbb[NG];
    __shared__ float sag[NG];
    __shared__ int sid[NG];
    if (threadIdx.x < NG) {
        float4 q = ((const float4*)bb)[b * NG + threadIdx.x];
        sbb[threadIdx.x] = q;
        sag[threadIdx.x] = (q.z - q.x) * (q.w - q.y);
        sid[threadIdx.x] = ids[b * NG + threadIdx.x];
    }
    __syncthreads();

    float bestv[NG];
    unsigned int bestn[NG];
#pragma unroll
    for (int g = 0; g < NG; ++g) { bestv[g] = -1.0f; bestn[g] = 0u; }

    const int iters = count >> 6;   // 4 (or 3 for last range)
    for (int k = 0; k < iters; ++k) {
        const int n = start + (k << 6) + lane;
        const float4 an = ((const float4*)anchors)[n];
        const float aa = (an.z - an.x) * (an.w - an.y);

        float abest = -1.0f;
        int agid = 0;
#pragma unroll
        for (int g = 0; g < NG; ++g) {
            const float4 q = sbb[g];
            float x1 = fmaxf(an.x, q.x);
            float y1 = fmaxf(an.y, q.y);
            float x2 = fminf(an.z, q.z);
            float y2 = fminf(an.w, q.w);
            float w = fmaxf(x2 - x1, 0.0f);
            float h = fmaxf(y2 - y1, 0.0f);
            float inter = w * h;
            float denom = aa + sag[g] - inter + 1e-9f;
            float v = inter / denom;
            if (v > bestv[g]) { bestv[g] = v; bestn[g] = (unsigned int)n; }
            if (v > abest) { abest = v; agid = g; }   // first argmax over g
        }

        float label;
        float4 rg;
        if (abest >= 0.5f) {
            const float4 gtb = sbb[agid];
            label = (float)sid[agid];
            float aw = an.z - an.x;
            float ah = an.w - an.y;
            float ax = an.x + 0.5f * aw;
            float ay = an.y + 0.5f * ah;
            float gw = gtb.z - gtb.x;
            float gh = gtb.w - gtb.y;
            float gx = gtb.x + 0.5f * gw;
            float gy = gtb.y + 0.5f * gh;
            rg = make_float4((gx - ax) / aw, (gy - ay) / ah, logf(gw / aw), logf(gh / ah));
        } else {
            label = (abest >= 0.4f) ? -1.0f : 0.0f;
            rg = make_float4(0.0f, 0.0f, 0.0f, 0.0f);
        }
        out[b * A_TOTAL + n] = label;
        ((float4*)(out + NB * A_TOTAL))[b * A_TOTAL + n] = rg;
    }

    // Per-g cross-lane reduction: key = (iou_bits << 32) | ~n  (ties -> smaller n).
    unsigned long long mykey = 0ull;
#pragma unroll
    for (int g = 0; g < NG; ++g) {
        unsigned long long key =
            ((unsigned long long)__float_as_uint(bestv[g]) << 32) |
            (unsigned long long)(~bestn[g]);
#pragma unroll
        for (int s = 1; s < 64; s <<= 1) {
            unsigned long long o = __shfl_xor(key, s, 64);
            key = (o > key) ? o : key;
        }
        if (lane == g) mykey = key;
    }
    if (lane < NG) {
        atomicMax(&part[(b * NG + lane) * NLVL + lvl], mykey);
    }
}

// Kernel B: per (b,g) pick best level (strict >, first level wins) -> forced anchor.
__global__ void reduce_kernel(const unsigned long long* __restrict__ part,
                              int* __restrict__ forced)
{
    const int i = threadIdx.x;           // 0..511
    if (i >= NB * NG) return;
    const unsigned long long* p = part + i * NLVL;
    unsigned long long k0 = p[0];
    unsigned int bestf = (unsigned int)(k0 >> 32);
    unsigned long long bestk = k0;
#pragma unroll
    for (int l = 1; l < NLVL; ++l) {
        unsigned long long kl = p[l];
        unsigned int f = (unsigned int)(kl >> 32);
        if (f > bestf) { bestf = f; bestk = kl; }  // first level wins ties
    }
    forced[i] = (int)(~(unsigned int)(bestk & 0xFFFFFFFFull));
}

// Kernel C: overwrite forced anchors. One thread per image, sequential over g
// so duplicate forced anchors resolve last-g-wins (matches verified semantics).
__global__ void fixup_kernel(const float* __restrict__ bb,
                             const int* __restrict__ ids,
                             const float* __restrict__ anchors,
                             const int* __restrict__ forced,
                             float* __restrict__ out)
{
    const int b = threadIdx.x;
    if (b >= NB) return;
    for (int g = 0; g < NG; ++g) {
        const int n = forced[b * NG + g];
        const float4 gtb = ((const float4*)bb)[b * NG + g];
        const float4 an = ((const float4*)anchors)[n];
        float aw = an.z - an.x;
        float ah = an.w - an.y;
        float ax = an.x + 0.5f * aw;
        float ay = an.y + 0.5f * ah;
        float gw = gtb.z - gtb.x;
        float gh = gtb.w - gtb.y;
        float gx = gtb.x + 0.5f * gw;
        float gy = gtb.y + 0.5f * gh;
        out[b * A_TOTAL + n] = (float)ids[b * NG + g];
        ((float4*)(out + NB * A_TOTAL))[b * A_TOTAL + n] =
            make_float4((gx - ax) / aw, (gy - ay) / ah, logf(gw / aw), logf(gh / ah));
    }
}

extern "C" void kernel_launch(void* const* d_in, const int* in_sizes, int n_in,
                              void* d_out, int out_size, void* d_ws, size_t ws_size,
                              hipStream_t stream) {
    const float* bb      = (const float*)d_in[0];
    const int*   ids     = (const int*)d_in[1];
    const float* anchors = (const float*)d_in[2];
    float* out = (float*)d_out;

    unsigned long long* part = (unsigned long long*)d_ws;          // 16*32*5*8 = 20480 B
    int* forced = (int*)((char*)d_ws + NB * NG * NLVL * sizeof(unsigned long long)); // 2 KB

    hipMemsetAsync(part, 0, NB * NG * NLVL * sizeof(unsigned long long), stream);
    hipLaunchKernelGGL(fused_kernel, dim3(NB * 64), dim3(256), 0, stream,
                       bb, ids, anchors, part, out);
    hipLaunchKernelGGL(reduce_kernel, dim3(1), dim3(512), 0, stream, part, forced);
    hipLaunchKernelGGL(fixup_kernel, dim3(1), dim3(64), 0, stream,
                       bb, ids, anchors, forced, out);
}

// Round 11
// 133.196 us; speedup vs baseline: 1.6241x; 1.6241x over previous
//
#include <hip/hip_runtime.h>

#pragma clang fp contract(off)

#define A_TOTAL 65472
#define NB 16
#define NG 32
#define NLVL 5

// 256-anchor ranges are level-uniform: r<192 -> L0, <240 -> L1, <252 -> L2,
// <255 -> L3, r==255 -> L4 (count 192).

__global__ __launch_bounds__(256) void fused_kernel(
    const float* __restrict__ bb,       // [NB][NG][4]
    const int* __restrict__ ids,        // [NB][NG]
    const float* __restrict__ anchors,  // [A_TOTAL][4]
    unsigned long long* __restrict__ part, // [NB][NG][NLVL], pre-zeroed
    float* __restrict__ out)            // labels [NB*A] then regs [NB*A*4]
{
    const int wid = threadIdx.x >> 6;
    const int lane = threadIdx.x & 63;
    const int b = blockIdx.x >> 6;                 // 64 blocks per image
    const int r = ((blockIdx.x & 63) << 2) + wid;  // range 0..255
    const int start = r << 8;
    const bool full = (r != 255);                  // last range: 192 anchors
    const int lvl = (r < 192) ? 0 : (r < 240) ? 1 : (r < 252) ? 2 : (r < 255) ? 3 : 4;

    __shared__ float4 sbb[NG];
    __shared__ float sag[NG];
    __shared__ int sid[NG];
    if (threadIdx.x < NG) {
        float4 q = ((const float4*)bb)[b * NG + threadIdx.x];
        sbb[threadIdx.x] = q;
        sag[threadIdx.x] = (q.z - q.x) * (q.w - q.y);
        sid[threadIdx.x] = ids[b * NG + threadIdx.x];
    }
    __syncthreads();

    // per-anchor (per-k) best over ALL g, carried across both g-halves
    float abest[4];
    int   agid[4];
#pragma unroll
    for (int k = 0; k < 4; ++k) { abest[k] = -1.0f; agid[k] = 0; }

    unsigned long long red = 0ull;  // lane<32: reduced key for g==lane

#pragma unroll
    for (int h = 0; h < 2; ++h) {
        // 16 per-g keys live only within this half  -> ~32 VGPRs, retired below
        unsigned long long key[16];
#pragma unroll
        for (int gi = 0; gi < 16; ++gi) key[gi] = 0ull;

#pragma unroll
        for (int k = 0; k < 4; ++k) {
            if (k == 3 && !full) continue;         // wave-uniform skip
            const int n = start + (k << 6) + lane;
            const float4 an = ((const float4*)anchors)[n];
            const float aa = (an.z - an.x) * (an.w - an.y);
#pragma unroll
            for (int gi = 0; gi < 16; ++gi) {
                const int g = h * 16 + gi;
                const float4 q = sbb[g];
                float x1 = fmaxf(an.x, q.x);
                float y1 = fmaxf(an.y, q.y);
                float x2 = fminf(an.z, q.z);
                float y2 = fminf(an.w, q.w);
                float w  = fmaxf(x2 - x1, 0.0f);
                float hh = fmaxf(y2 - y1, 0.0f);
                float inter = w * hh;
                float denom = aa + sag[g] - inter + 1e-9f;
                float v = inter / denom;
                // key: larger iou wins; tie -> larger ~n = smaller n (first argmax).
                // n ascends within a lane, so strict > also keeps first per-lane.
                unsigned long long kk =
                    ((unsigned long long)__float_as_uint(v) << 32) |
                    (unsigned long long)(~(unsigned int)n);
                if (kk > key[gi]) key[gi] = kk;
                if (v > abest[k]) { abest[k] = v; agid[k] = g; }  // first argmax over g
            }
        }
        // cross-lane max-reduce each key; park result in lane g
#pragma unroll
        for (int gi = 0; gi < 16; ++gi) {
            unsigned long long kx = key[gi];
#pragma unroll
            for (int s = 1; s < 64; s <<= 1) {
                unsigned long long o = __shfl_xor(kx, s, 64);
                kx = (o > kx) ? o : kx;
            }
            if (lane == h * 16 + gi) red = kx;
        }
    }
    if (lane < NG) {
        atomicMax(&part[(b * NG + lane) * NLVL + lvl], red);
    }

    // per-anchor outputs (anchor reloads hit L1)
#pragma unroll
    for (int k = 0; k < 4; ++k) {
        if (k == 3 && !full) continue;
        const int n = start + (k << 6) + lane;
        const float4 an = ((const float4*)anchors)[n];
        float label;
        float4 rg;
        if (abest[k] >= 0.5f) {
            const float4 gtb = sbb[agid[k]];
            label = (float)sid[agid[k]];
            float aw = an.z - an.x;
            float ah = an.w - an.y;
            float ax = an.x + 0.5f * aw;
            float ay = an.y + 0.5f * ah;
            float gw = gtb.z - gtb.x;
            float gh = gtb.w - gtb.y;
            float gx = gtb.x + 0.5f * gw;
            float gy = gtb.y + 0.5f * gh;
            rg = make_float4((gx - ax) / aw, (gy - ay) / ah, logf(gw / aw), logf(gh / ah));
        } else {
            label = (abest[k] >= 0.4f) ? -1.0f : 0.0f;
            rg = make_float4(0.0f, 0.0f, 0.0f, 0.0f);
        }
        out[b * A_TOTAL + n] = label;
        ((float4*)(out + NB * A_TOTAL))[b * A_TOTAL + n] = rg;
    }
}

// Kernel B: per (b,g) pick best level (strict >, first level wins) -> forced anchor.
__global__ void reduce_kernel(const unsigned long long* __restrict__ part,
                              int* __restrict__ forced)
{
    const int i = threadIdx.x;           // 0..511
    if (i >= NB * NG) return;
    const unsigned long long* p = part + i * NLVL;
    unsigned long long k0 = p[0];
    unsigned int bestf = (unsigned int)(k0 >> 32);
    unsigned long long bestk = k0;
#pragma unroll
    for (int l = 1; l < NLVL; ++l) {
        unsigned long long kl = p[l];
        unsigned int f = (unsigned int)(kl >> 32);
        if (f > bestf) { bestf = f; bestk = kl; }  // first level wins ties
    }
    forced[i] = (int)(~(unsigned int)(bestk & 0xFFFFFFFFull));
}

// Kernel C: overwrite forced anchors. One thread per image, sequential over g
// so duplicate forced anchors resolve last-g-wins.
__global__ void fixup_kernel(const float* __restrict__ bb,
                             const int* __restrict__ ids,
                             const float* __restrict__ anchors,
                             const int* __restrict__ forced,
                             float* __restrict__ out)
{
    const int b = threadIdx.x;
    if (b >= NB) return;
    for (int g = 0; g < NG; ++g) {
        const int n = forced[b * NG + g];
        const float4 gtb = ((const float4*)bb)[b * NG + g];
        const float4 an = ((const float4*)anchors)[n];
        float aw = an.z - an.x;
        float ah = an.w - an.y;
        float ax = an.x + 0.5f * aw;
        float ay = an.y + 0.5f * ah;
        float gw = gtb.z - gtb.x;
        float gh = gtb.w - gtb.y;
        float gx = gtb.x + 0.5f * gw;
        float gy = gtb.y + 0.5f * gh;
        out[b * A_TOTAL + n] = (float)ids[b * NG + g];
        ((float4*)(out + NB * A_TOTAL))[b * A_TOTAL + n] =
            make_float4((gx - ax) / aw, (gy - ay) / ah, logf(gw / aw), logf(gh / ah));
    }
}

extern "C" void kernel_launch(void* const* d_in, const int* in_sizes, int n_in,
                              void* d_out, int out_size, void* d_ws, size_t ws_size,
                              hipStream_t stream) {
    const float* bb      = (const float*)d_in[0];
    const int*   ids     = (const int*)d_in[1];
    const float* anchors = (const float*)d_in[2];
    float* out = (float*)d_out;

    unsigned long long* part = (unsigned long long*)d_ws;          // 20480 B
    int* forced = (int*)((char*)d_ws + NB * NG * NLVL * sizeof(unsigned long long));

    hipMemsetAsync(part, 0, NB * NG * NLVL * sizeof(unsigned long long), stream);
    hipLaunchKernelGGL(fused_kernel, dim3(NB * 64), dim3(256), 0, stream,
                       bb, ids, anchors, part, out);
    hipLaunchKernelGGL(reduce_kernel, dim3(1), dim3(512), 0, stream, part, forced);
    hipLaunchKernelGGL(fixup_kernel, dim3(1), dim3(64), 0, stream,
                       bb, ids, anchors, forced, out);
}

// Round 12
// 118.503 us; speedup vs baseline: 1.8254x; 1.1240x over previous
//
#include <hip/hip_runtime.h>

#pragma clang fp contract(off)

#define A_TOTAL 65472
#define NB 16
#define NG 32
#define NLVL 5

// Wave-ranges of 128 anchors (512 per image): w<384 -> L0, <480 -> L1,
// <504 -> L2, <510 -> L3, else L4. Wave 511 covers only 64 valid anchors.

__global__ __launch_bounds__(256) void fused_kernel(
    const float* __restrict__ bb,       // [NB][NG][4]
    const int* __restrict__ ids,        // [NB][NG]
    const float* __restrict__ anchors,  // [A_TOTAL][4]
    unsigned long long* __restrict__ part, // [NB][NG][NLVL], pre-zeroed
    float* __restrict__ out)            // labels [NB*A] then regs [NB*A*4]
{
    const int wid  = threadIdx.x >> 6;
    const int lane = threadIdx.x & 63;
    const int b = blockIdx.x >> 7;                   // 128 blocks per image
    const int w = ((blockIdx.x & 127) << 2) + wid;   // wave-range 0..511
    const int start = w << 7;
    const bool full = (w != 511);
    const int lvl = (w < 384) ? 0 : (w < 480) ? 1 : (w < 504) ? 2 : (w < 510) ? 3 : 4;

    __shared__ float4 sbb[NG];
    __shared__ float  sag[NG];
    __shared__ int    sid[NG];
    if (threadIdx.x < NG) {
        float4 q = ((const float4*)bb)[b * NG + threadIdx.x];
        sbb[threadIdx.x] = q;
        sag[threadIdx.x] = (q.z - q.x) * (q.w - q.y);
        sid[threadIdx.x] = ids[b * NG + threadIdx.x];
    }
    __syncthreads();

    // two anchors per lane, held in registers for all 32 g
    float4 an[2];
    float  aa[2];
    an[0] = ((const float4*)anchors)[start + lane];
    aa[0] = (an[0].z - an[0].x) * (an[0].w - an[0].y);
    if (full) {
        an[1] = ((const float4*)anchors)[start + 64 + lane];
        aa[1] = (an[1].z - an[1].x) * (an[1].w - an[1].y);
    } else {
        an[1] = an[0]; aa[1] = aa[0];   // never used
    }

    float abest[2] = {-1.0f, -1.0f};
    int   agid[2]  = {0, 0};
    unsigned long long red = 0ull;      // lane<32: reduced key for g==lane

    for (int g = 0; g < NG; ++g) {
        const float4 q  = sbb[g];
        const float  ag = sag[g];
        unsigned long long key = 0ull;
#pragma unroll
        for (int k = 0; k < 2; ++k) {
            if (k == 1 && !full) continue;          // wave-uniform skip
            const unsigned int n = (unsigned int)(start + (k << 6) + lane);
            float x1 = fmaxf(an[k].x, q.x);
            float y1 = fmaxf(an[k].y, q.y);
            float x2 = fminf(an[k].z, q.z);
            float y2 = fminf(an[k].w, q.w);
            float ww = fmaxf(x2 - x1, 0.0f);
            float hh = fmaxf(y2 - y1, 0.0f);
            float inter = ww * hh;
            float denom = aa[k] + ag - inter + 1e-9f;
            float v = inter / denom;
            // key: larger iou wins; tie -> larger ~n = smaller n (first argmax).
            unsigned long long kk =
                ((unsigned long long)__float_as_uint(v) << 32) |
                (unsigned long long)(~n);
            if (kk > key) key = kk;
            if (v > abest[k]) { abest[k] = v; agid[k] = g; }  // first argmax over g
        }
        // 64-lane max-reduce; park result in lane g
#pragma unroll
        for (int s = 1; s < 64; s <<= 1) {
            unsigned long long o = __shfl_xor(key, s, 64);
            if (o > key) key = o;
        }
        if (lane == g) red = key;
    }
    if (lane < NG) {
        atomicMax(&part[(b * NG + lane) * NLVL + lvl], red);
    }

    // per-anchor outputs
#pragma unroll
    for (int k = 0; k < 2; ++k) {
        if (k == 1 && !full) continue;
        const int n = start + (k << 6) + lane;
        float label;
        float4 rg;
        if (abest[k] >= 0.5f) {
            const float4 gtb = sbb[agid[k]];
            label = (float)sid[agid[k]];
            float aw = an[k].z - an[k].x;
            float ah = an[k].w - an[k].y;
            float ax = an[k].x + 0.5f * aw;
            float ay = an[k].y + 0.5f * ah;
            float gw = gtb.z - gtb.x;
            float gh = gtb.w - gtb.y;
            float gx = gtb.x + 0.5f * gw;
            float gy = gtb.y + 0.5f * gh;
            rg = make_float4((gx - ax) / aw, (gy - ay) / ah, logf(gw / aw), logf(gh / ah));
        } else {
            label = (abest[k] >= 0.4f) ? -1.0f : 0.0f;
            rg = make_float4(0.0f, 0.0f, 0.0f, 0.0f);
        }
        out[b * A_TOTAL + n] = label;
        ((float4*)(out + NB * A_TOTAL))[b * A_TOTAL + n] = rg;
    }
}

// Tail: one block, 512 threads = (b,g). Level-pick (strict >, first level wins)
// then parallel forced-overwrite with last-g-wins dedup.
__global__ __launch_bounds__(512) void tail_kernel(
    const float* __restrict__ bb,
    const int* __restrict__ ids,
    const float* __restrict__ anchors,
    unsigned long long* __restrict__ part,
    float* __restrict__ out)
{
    const int t = threadIdx.x;          // 0..511
    __shared__ int sfor[NB * NG];

    // atomic reads: coherent view of fused kernel's device-scope atomics
    unsigned long long k0 = atomicMax(&part[t * NLVL + 0], 0ull);
    unsigned int bestf = (unsigned int)(k0 >> 32);
    unsigned long long bestk = k0;
#pragma unroll
    for (int l = 1; l < NLVL; ++l) {
        unsigned long long kl = atomicMax(&part[t * NLVL + l], 0ull);
        unsigned int f = (unsigned int)(kl >> 32);
        if (f > bestf) { bestf = f; bestk = kl; }   // first level wins ties
    }
    const int n = (int)(~(unsigned int)(bestk & 0xFFFFFFFFull));
    sfor[t] = n;
    __syncthreads();

    const int b = t >> 5;
    const int g = t & 31;
    bool shadowed = false;
    for (int g2 = g + 1; g2 < NG; ++g2)
        if (sfor[(b << 5) | g2] == n) shadowed = true;  // later g overwrites

    if (!shadowed) {
        const float4 gtb = ((const float4*)bb)[t];
        const float4 an  = ((const float4*)anchors)[n];
        float aw = an.z - an.x;
        float ah = an.w - an.y;
        float ax = an.x + 0.5f * aw;
        float ay = an.y + 0.5f * ah;
        float gw = gtb.z - gtb.x;
        float gh = gtb.w - gtb.y;
        float gx = gtb.x + 0.5f * gw;
        float gy = gtb.y + 0.5f * gh;
        out[b * A_TOTAL + n] = (float)ids[t];
        ((float4*)(out + NB * A_TOTAL))[b * A_TOTAL + n] =
            make_float4((gx - ax) / aw, (gy - ay) / ah, logf(gw / aw), logf(gh / ah));
    }
}

extern "C" void kernel_launch(void* const* d_in, const int* in_sizes, int n_in,
                              void* d_out, int out_size, void* d_ws, size_t ws_size,
                              hipStream_t stream) {
    const float* bb      = (const float*)d_in[0];
    const int*   ids     = (const int*)d_in[1];
    const float* anchors = (const float*)d_in[2];
    float* out = (float*)d_out;

    unsigned long long* part = (unsigned long long*)d_ws;   // 16*32*5*8 = 20480 B

    hipMemsetAsync(part, 0, NB * NG * NLVL * sizeof(unsigned long long), stream);
    hipLaunchKernelGGL(fused_kernel, dim3(NB * 128), dim3(256), 0, stream,
                       bb, ids, anchors, part, out);
    hipLaunchKernelGGL(tail_kernel, dim3(1), dim3(512), 0, stream,
                       bb, ids, anchors, part, out);
}